// Round 1
// baseline (2174.999 us; speedup 1.0000x reference)
//
#include <hip/hip_runtime.h>
#include <hip/hip_bf16.h>
#include <cstdint>
#include <cstddef>

// Problem constants (T5 self-attention, B=2, S=2048, H=16, D=64, d_model=1024)
#define S_LEN 2048
#define NH 16
#define DKV 64
#define BATCH 2
#define DMODEL 1024

// ---------------------------------------------------------------------------
// T5 relative-position bucket, bidirectional, num_buckets=32, max_distance=128.
// Computed with EXACT integer thresholds (boundaries ceil(8*16^(n/8))):
//   large-range bucket n for |d| in: 8..11->8, 12..15->9, 16..22->10, 23..31->11,
//   32..45->12, 46..63->13, 64..90->14, 91+->15 (capped).
// Verified analytically to agree with the fp32 reference at all integer deltas.
// ---------------------------------------------------------------------------
__device__ __forceinline__ int t5_bucket(int delta) {
  int base = (delta > 0) ? 16 : 0;
  int a = delta < 0 ? -delta : delta;
  int n;
  if (a < 8)       n = a;
  else if (a < 12) n = 8;
  else if (a < 16) n = 9;
  else if (a < 23) n = 10;
  else if (a < 32) n = 11;
  else if (a < 46) n = 12;
  else if (a < 64) n = 13;
  else if (a < 91) n = 14;
  else             n = 15;
  return base + n;
}

// ---------------------------------------------------------------------------
// position_bias output: out[(h*S + q)*S + k] = table[bucket(k-q)*NH + h]
// grid = NH*S blocks (blockIdx.x = h*S + q), 256 threads, 8 floats/thread.
// Memory-bound: 268 MB write.
// ---------------------------------------------------------------------------
__global__ __launch_bounds__(256) void bias_kernel(const float* __restrict__ table,
                                                   float* __restrict__ out) {
  int h = blockIdx.x >> 11;
  int q = blockIdx.x & (S_LEN - 1);
  __shared__ float tb[32];
  if (threadIdx.x < 32) tb[threadIdx.x] = table[threadIdx.x * NH + h];
  __syncthreads();
  float* dst = out + (size_t)blockIdx.x * S_LEN;
  int k0 = threadIdx.x * 4;
#pragma unroll
  for (int half = 0; half < 2; half++) {
    int k = k0 + half * 1024;
    float4 v;
    v.x = tb[t5_bucket((k + 0) - q)];
    v.y = tb[t5_bucket((k + 1) - q)];
    v.z = tb[t5_bucket((k + 2) - q)];
    v.w = tb[t5_bucket((k + 3) - q)];
    *(float4*)(dst + k) = v;
  }
}

// ---------------------------------------------------------------------------
// fp32 tiled GEMM: C[M,N] = A[M,K] @ B[K,N], all row-major.
// 128x128 block tile, BK=8, 256 threads, 8x8 micro-tile per thread.
// MODE 0: plain store to C.
// MODE 1: QKV scatter epilogue: col c -> which=c/1024, h=(c%1024)/64, d=c%64;
//         row r -> b=r/S, s=r%S; store to {Q,K,V}[((b*NH+h)*S + s)*DKV + d].
// Requires M%128==0, N%128==0, K%8==0 (true here: 4096 x {3072,1024} x 1024).
// ---------------------------------------------------------------------------
template <int MODE>
__global__ __launch_bounds__(256) void sgemm128(const float* __restrict__ A,
                                                const float* __restrict__ B,
                                                float* __restrict__ C,
                                                float* __restrict__ Qo,
                                                float* __restrict__ Ko,
                                                float* __restrict__ Vo,
                                                int M, int N, int K) {
  __shared__ float As[8][128];   // [k][m] (A transposed in LDS)
  __shared__ float Bs[8][128];   // [k][n]

  const int tid = threadIdx.x;
  const int m0 = blockIdx.y * 128;
  const int n0 = blockIdx.x * 128;

  const int ty = tid >> 4;       // 0..15 -> row group (8 rows each)
  const int tx = tid & 15;       // 0..15 -> col group (8 cols each)

  // A-load assignment: 128x8 tile, 4 floats (one float4) per thread
  const int a_row = tid >> 1;          // 0..127
  const int a_col = (tid & 1) * 4;     // 0 or 4
  // B-load assignment: 8x128 tile, one float4 per thread
  const int b_row = tid >> 5;          // 0..7
  const int b_col = (tid & 31) * 4;    // 0..124

  float acc[8][8];
#pragma unroll
  for (int i = 0; i < 8; i++)
#pragma unroll
    for (int j = 0; j < 8; j++) acc[i][j] = 0.0f;

  for (int k0 = 0; k0 < K; k0 += 8) {
    float4 av = *(const float4*)(A + (size_t)(m0 + a_row) * K + k0 + a_col);
    float4 bv = *(const float4*)(B + (size_t)(k0 + b_row) * N + n0 + b_col);
    __syncthreads();  // previous tile's compute done before overwrite
    As[a_col + 0][a_row] = av.x;
    As[a_col + 1][a_row] = av.y;
    As[a_col + 2][a_row] = av.z;
    As[a_col + 3][a_row] = av.w;
    *(float4*)&Bs[b_row][b_col] = bv;
    __syncthreads();
#pragma unroll
    for (int kk = 0; kk < 8; kk++) {
      float4 a0 = *(float4*)&As[kk][ty * 8];
      float4 a1 = *(float4*)&As[kk][ty * 8 + 4];
      float4 b0 = *(float4*)&Bs[kk][tx * 8];
      float4 b1 = *(float4*)&Bs[kk][tx * 8 + 4];
      float ar[8] = {a0.x, a0.y, a0.z, a0.w, a1.x, a1.y, a1.z, a1.w};
      float br[8] = {b0.x, b0.y, b0.z, b0.w, b1.x, b1.y, b1.z, b1.w};
#pragma unroll
      for (int i = 0; i < 8; i++)
#pragma unroll
        for (int j = 0; j < 8; j++) acc[i][j] += ar[i] * br[j];
    }
  }

  if (MODE == 0) {
#pragma unroll
    for (int i = 0; i < 8; i++) {
      int row = m0 + ty * 8 + i;
      float* dst = C + (size_t)row * N + n0 + tx * 8;
      *(float4*)(dst + 0) = make_float4(acc[i][0], acc[i][1], acc[i][2], acc[i][3]);
      *(float4*)(dst + 4) = make_float4(acc[i][4], acc[i][5], acc[i][6], acc[i][7]);
    }
  } else {
    int c0 = n0 + tx * 8;          // 8 contiguous cols, all inside one head block
    int which = c0 >> 10;          // 0=q,1=k,2=v
    int r1 = c0 & 1023;
    int h = r1 >> 6;
    int d0 = r1 & 63;
    float* base = (which == 0) ? Qo : (which == 1) ? Ko : Vo;
#pragma unroll
    for (int i = 0; i < 8; i++) {
      int row = m0 + ty * 8 + i;
      int b = row >> 11;
      int s = row & (S_LEN - 1);
      float* dst = base + ((size_t)(b * NH + h) * S_LEN + s) * DKV + d0;
      *(float4*)(dst + 0) = make_float4(acc[i][0], acc[i][1], acc[i][2], acc[i][3]);
      *(float4*)(dst + 4) = make_float4(acc[i][4], acc[i][5], acc[i][6], acc[i][7]);
    }
  }
}

// ---------------------------------------------------------------------------
// fp32 flash attention with T5 relative bias (no 1/sqrt(d) scale).
// grid = (S/16, BATCH*NH); block = 256 threads = 4 waves.
// Each wave owns 4 query rows; lanes act as k-index (scores) then d-index (PV).
// K/V chunk (64 x 64) staged in LDS with +1 padding -> conflict-free b32 reads.
// Online softmax (m, l per row) with wave shuffle reductions.
// Writes X[b*S + q][h*64 + d] (layout ready for the output projection GEMM).
// ---------------------------------------------------------------------------
__device__ __forceinline__ float wave_max(float v) {
#pragma unroll
  for (int m = 1; m <= 32; m <<= 1) v = fmaxf(v, __shfl_xor(v, m));
  return v;
}
__device__ __forceinline__ float wave_sum(float v) {
#pragma unroll
  for (int m = 1; m <= 32; m <<= 1) v += __shfl_xor(v, m);
  return v;
}

__global__ __launch_bounds__(256) void attn_kernel(const float* __restrict__ Q,
                                                   const float* __restrict__ K,
                                                   const float* __restrict__ V,
                                                   const float* __restrict__ table,
                                                   float* __restrict__ X) {
  __shared__ float Ks[64 * 65];
  __shared__ float Vs[64 * 65];
  __shared__ float qs[16 * 64];
  __shared__ float pls[16 * 64];  // p values: [wave*4+r][j]
  __shared__ float tb[32];

  const int tid = threadIdx.x;
  const int w = tid >> 6;
  const int lane = tid & 63;
  const int bh = blockIdx.y;       // b*NH + h
  const int h = bh & (NH - 1);
  const int b = bh >> 4;
  const int q0 = blockIdx.x * 16;

  if (tid < 32) tb[tid] = table[tid * NH + h];
  // stage the block's 16 q rows
  {
    int r = tid >> 4;              // 0..15
    int d4 = (tid & 15) * 4;
    float4 qv = *(const float4*)(Q + ((size_t)bh * S_LEN + q0 + r) * DKV + d4);
    *(float4*)&qs[r * DKV + d4] = qv;
  }

  float m[4], l[4], o[4];
#pragma unroll
  for (int r = 0; r < 4; r++) { m[r] = -1e30f; l[r] = 0.0f; o[r] = 0.0f; }

  const int jr = tid >> 2;            // 0..63 (staging row)
  const int dbase = (tid & 3) * 16;   // staging col base

  for (int kc = 0; kc < S_LEN; kc += 64) {
    __syncthreads();  // previous chunk's compute done (also covers qs/tb on iter 0... barrier below does)
    // stage K and V chunk [64 x 64] with stride 65
    const float* Kg = K + ((size_t)bh * S_LEN + kc + jr) * DKV + dbase;
    const float* Vg = V + ((size_t)bh * S_LEN + kc + jr) * DKV + dbase;
#pragma unroll
    for (int t = 0; t < 4; t++) {
      float4 kv = *(const float4*)(Kg + t * 4);
      float4 vv = *(const float4*)(Vg + t * 4);
      int bi = jr * 65 + dbase + t * 4;
      Ks[bi + 0] = kv.x; Ks[bi + 1] = kv.y; Ks[bi + 2] = kv.z; Ks[bi + 3] = kv.w;
      Vs[bi + 0] = vv.x; Vs[bi + 1] = vv.y; Vs[bi + 2] = vv.z; Vs[bi + 3] = vv.w;
    }
    __syncthreads();

    // Phase A: scores. lane = j (k-position within chunk). 4 rows fused.
    float s[4] = {0.0f, 0.0f, 0.0f, 0.0f};
    const float* qb = &qs[(w * 4) * DKV];
#pragma unroll 8
    for (int d = 0; d < 64; d++) {
      float kv = Ks[lane * 65 + d];   // conflict-free: bank (lane+d)%32
      s[0] += qb[d] * kv;             // broadcast reads
      s[1] += qb[64 + d] * kv;
      s[2] += qb[128 + d] * kv;
      s[3] += qb[192 + d] * kv;
    }

    // bias + online softmax per row
    float al[4];
#pragma unroll
    for (int r = 0; r < 4; r++) {
      int qabs = q0 + w * 4 + r;
      s[r] += tb[t5_bucket((kc + lane) - qabs)];
      float cm = wave_max(s[r]);
      float mn = fmaxf(m[r], cm);
      al[r] = __expf(m[r] - mn);
      float p = __expf(s[r] - mn);
      l[r] = l[r] * al[r] + wave_sum(p);
      m[r] = mn;
      pls[(w * 4 + r) * 64 + lane] = p;   // wave-private region; no barrier needed
    }

    // Phase B: O += P @ V. lane = d. 4 rows fused.
#pragma unroll
    for (int r = 0; r < 4; r++) o[r] *= al[r];
    const float* pb = &pls[(w * 4) * 64];
#pragma unroll 8
    for (int j = 0; j < 64; j++) {
      float vv = Vs[j * 65 + lane];   // conflict-free
      o[0] += pb[j] * vv;             // broadcast reads
      o[1] += pb[64 + j] * vv;
      o[2] += pb[128 + j] * vv;
      o[3] += pb[192 + j] * vv;
    }
  }

#pragma unroll
  for (int r = 0; r < 4; r++) {
    int row = b * S_LEN + q0 + w * 4 + r;
    X[(size_t)row * DMODEL + h * DKV + lane] = o[r] / l[r];
  }
}

// ---------------------------------------------------------------------------
// kernel_launch
// d_in: 0=hidden_states [2,2048,1024] f32, 1=w_qkv [1024,3072] f32,
//       2=w_o [1024,1024] f32, 3=rel_bias_table [32,16] f32
// d_out: attn_output [2,2048,1024] (4,194,304 f32) then
//        position_bias [1,16,2048,2048] (67,108,864 f32)
// ws: Q,K,V in [b,h,s,d] (3 x 4,194,304 f32) + X [4096,1024] (4,194,304 f32)
// ---------------------------------------------------------------------------
extern "C" void kernel_launch(void* const* d_in, const int* in_sizes, int n_in,
                              void* d_out, int out_size, void* d_ws, size_t ws_size,
                              hipStream_t stream) {
  const float* hidden = (const float*)d_in[0];
  const float* w_qkv = (const float*)d_in[1];
  const float* w_o = (const float*)d_in[2];
  const float* table = (const float*)d_in[3];

  float* attn_out = (float*)d_out;                 // 4,194,304 floats
  float* bias_out = (float*)d_out + 4194304;       // 67,108,864 floats

  float* ws = (float*)d_ws;
  float* Qw = ws;
  float* Kw = ws + 4194304;
  float* Vw = ws + 8388608;
  float* Xw = ws + 12582912;

  // 1) position_bias (independent of everything else)
  bias_kernel<<<NH * S_LEN, 256, 0, stream>>>(table, bias_out);

  // 2) QKV projection: [4096,1024] @ [1024,3072], scatter into Q/K/V [b,h,s,d]
  sgemm128<1><<<dim3(3072 / 128, 4096 / 128), 256, 0, stream>>>(
      hidden, w_qkv, nullptr, Qw, Kw, Vw, 4096, 3072, 1024);

  // 3) flash attention with inline T5 bias -> X [4096,1024]
  attn_kernel<<<dim3(S_LEN / 16, BATCH * NH), 256, 0, stream>>>(Qw, Kw, Vw, table, Xw);

  // 4) output projection: [4096,1024] @ [1024,1024] -> d_out
  sgemm128<0><<<dim3(1024 / 128, 4096 / 128), 256, 0, stream>>>(
      Xw, w_o, attn_out, nullptr, nullptr, nullptr, 4096, 1024, 1024);
}

// Round 2
// 965.183 us; speedup vs baseline: 2.2535x; 2.2535x over previous
//
#include <hip/hip_runtime.h>
#include <hip/hip_bf16.h>
#include <cstdint>
#include <cstddef>

// Problem constants (T5 self-attention, B=2, S=2048, H=16, D=64, d_model=1024)
#define S_LEN 2048
#define NH 16
#define DKV 64
#define BATCH 2
#define DMODEL 1024

typedef _Float16 half_t;
typedef __attribute__((ext_vector_type(8))) _Float16 half8;   // MFMA A/B frag (4 VGPRs)
typedef __attribute__((ext_vector_type(4))) float floatx4;    // MFMA C/D frag

// ---------------------------------------------------------------------------
// T5 relative-position bucket, bidirectional, num_buckets=32, max_distance=128.
// EXACT integer thresholds (boundaries ceil(8*16^(n/8))) — verified to agree
// with the fp32 reference at every integer delta.
// ---------------------------------------------------------------------------
__device__ __forceinline__ int t5_bucket(int delta) {
  int base = (delta > 0) ? 16 : 0;
  int a = delta < 0 ? -delta : delta;
  int n;
  if (a < 8)       n = a;
  else if (a < 12) n = 8;
  else if (a < 16) n = 9;
  else if (a < 23) n = 10;
  else if (a < 32) n = 11;
  else if (a < 46) n = 12;
  else if (a < 64) n = 13;
  else if (a < 91) n = 14;
  else             n = 15;
  return base + n;
}

// ---------------------------------------------------------------------------
// position_bias output: out[(h*S + q)*S + k] = table[bucket(k-q)*NH + h]
// Memory-bound: 268 MB write.
// ---------------------------------------------------------------------------
__global__ __launch_bounds__(256) void bias_kernel(const float* __restrict__ table,
                                                   float* __restrict__ out) {
  int h = blockIdx.x >> 11;
  int q = blockIdx.x & (S_LEN - 1);
  __shared__ float tb[32];
  if (threadIdx.x < 32) tb[threadIdx.x] = table[threadIdx.x * NH + h];
  __syncthreads();
  float* dst = out + (size_t)blockIdx.x * S_LEN;
  int k0 = threadIdx.x * 4;
#pragma unroll
  for (int half = 0; half < 2; half++) {
    int k = k0 + half * 1024;
    float4 v;
    v.x = tb[t5_bucket((k + 0) - q)];
    v.y = tb[t5_bucket((k + 1) - q)];
    v.z = tb[t5_bucket((k + 2) - q)];
    v.w = tb[t5_bucket((k + 3) - q)];
    *(float4*)(dst + k) = v;
  }
}

// ---------------------------------------------------------------------------
// fp32 tiled GEMM: C[M,N] = A[M,K] @ B[K,N], row-major. 128x128x8, 256 thr.
// MODE 0: plain fp32 store to C.
// MODE 1: QKV epilogue -> fp16: Q,K scattered to [b,h,s,d]; V scattered
//         TRANSPOSED to Vt[b,h,d,s] (ready as PV B-operand in attention).
// ---------------------------------------------------------------------------
template <int MODE>
__global__ __launch_bounds__(256) void sgemm128(const float* __restrict__ A,
                                                const float* __restrict__ B,
                                                float* __restrict__ C,
                                                half_t* __restrict__ Qo,
                                                half_t* __restrict__ Ko,
                                                half_t* __restrict__ Vto,
                                                int M, int N, int K) {
  __shared__ float As[8][128];   // [k][m]
  __shared__ float Bs[8][128];   // [k][n]

  const int tid = threadIdx.x;
  const int m0 = blockIdx.y * 128;
  const int n0 = blockIdx.x * 128;
  const int ty = tid >> 4;
  const int tx = tid & 15;
  const int a_row = tid >> 1;
  const int a_col = (tid & 1) * 4;
  const int b_row = tid >> 5;
  const int b_col = (tid & 31) * 4;

  float acc[8][8];
#pragma unroll
  for (int i = 0; i < 8; i++)
#pragma unroll
    for (int j = 0; j < 8; j++) acc[i][j] = 0.0f;

  for (int k0 = 0; k0 < K; k0 += 8) {
    float4 av = *(const float4*)(A + (size_t)(m0 + a_row) * K + k0 + a_col);
    float4 bv = *(const float4*)(B + (size_t)(k0 + b_row) * N + n0 + b_col);
    __syncthreads();
    As[a_col + 0][a_row] = av.x;
    As[a_col + 1][a_row] = av.y;
    As[a_col + 2][a_row] = av.z;
    As[a_col + 3][a_row] = av.w;
    *(float4*)&Bs[b_row][b_col] = bv;
    __syncthreads();
#pragma unroll
    for (int kk = 0; kk < 8; kk++) {
      float4 a0 = *(float4*)&As[kk][ty * 8];
      float4 a1 = *(float4*)&As[kk][ty * 8 + 4];
      float4 b0 = *(float4*)&Bs[kk][tx * 8];
      float4 b1 = *(float4*)&Bs[kk][tx * 8 + 4];
      float ar[8] = {a0.x, a0.y, a0.z, a0.w, a1.x, a1.y, a1.z, a1.w};
      float br[8] = {b0.x, b0.y, b0.z, b0.w, b1.x, b1.y, b1.z, b1.w};
#pragma unroll
      for (int i = 0; i < 8; i++)
#pragma unroll
        for (int j = 0; j < 8; j++) acc[i][j] += ar[i] * br[j];
    }
  }

  if (MODE == 0) {
#pragma unroll
    for (int i = 0; i < 8; i++) {
      int row = m0 + ty * 8 + i;
      float* dst = C + (size_t)row * N + n0 + tx * 8;
      *(float4*)(dst + 0) = make_float4(acc[i][0], acc[i][1], acc[i][2], acc[i][3]);
      *(float4*)(dst + 4) = make_float4(acc[i][4], acc[i][5], acc[i][6], acc[i][7]);
    }
  } else {
    int c0 = n0 + tx * 8;          // 8 contiguous cols within one head block
    int which = c0 >> 10;          // 0=q,1=k,2=v
    int r1 = c0 & 1023;
    int h = r1 >> 6;
    int d0 = r1 & 63;
    int row0 = m0 + ty * 8;        // 8 contiguous rows, same batch (m0 % 128 == 0)
    int b = row0 >> 11;
    int s0 = row0 & (S_LEN - 1);
    if (which < 2) {
      half_t* base = (which == 0) ? Qo : Ko;
#pragma unroll
      for (int i = 0; i < 8; i++) {
        half8 hv;
#pragma unroll
        for (int j = 0; j < 8; j++) hv[j] = (half_t)acc[i][j];
        *(half8*)(base + ((size_t)(b * NH + h) * S_LEN + s0 + i) * DKV + d0) = hv;
      }
    } else {
      // V transposed: Vt[((b*NH+h)*64 + d)*S + s]
#pragma unroll
      for (int j = 0; j < 8; j++) {
        half8 hv;
#pragma unroll
        for (int i = 0; i < 8; i++) hv[i] = (half_t)acc[i][j];
        *(half8*)(Vto + ((size_t)(b * NH + h) * DKV + d0 + j) * S_LEN + s0) = hv;
      }
    }
  }
}

// ---------------------------------------------------------------------------
// fp16 MFMA flash attention with T5 relative bias (no 1/sqrt(d) scale).
// grid = (S/64, BATCH*NH); block = 256 (4 waves). Wave w owns q rows
// q0 + w*16 .. +15. K-chunk = 64 keys staged in LDS each iteration.
//
// mfma_f32_16x16x32_f16 layouts (verified m89/m118/m120):
//   A: lane holds A[m=lane&15][k=quad*8+j], j=0..7 (quad=lane>>4)
//   B: lane holds B[k=quad*8+j][n=lane&15]
//   C/D: lane holds D[row=quad*4+reg][col=lane&15]
//
// LDS swizzle: 8-half units, physical_unit = unit ^ (row&7). Without it the
// 128B row stride puts every row on the same 4 banks (16-way conflict);
// with it each 16-lane phase of a ds_read_b128 covers all 32 banks.
// ---------------------------------------------------------------------------
__global__ __launch_bounds__(256) void attn_mfma(const half_t* __restrict__ Q,
                                                 const half_t* __restrict__ K,
                                                 const half_t* __restrict__ Vt,
                                                 const float* __restrict__ table,
                                                 float* __restrict__ X) {
  __shared__ half_t Ks[64 * 64];    // [key][d] swizzled
  __shared__ half_t Vts[64 * 64];   // [d][key] swizzled
  __shared__ half_t Ps[64 * 68];    // [q(64)][key(64)], stride 68
  __shared__ float tb[32];

  const int tid = threadIdx.x;
  const int w = tid >> 6;
  const int lane = tid & 63;
  const int l15 = lane & 15;
  const int quad = lane >> 4;
  const int bh = blockIdx.y;
  const int h = bh & (NH - 1);
  const int b = bh >> 4;
  const int q0 = blockIdx.x * 64;

  if (tid < 32) tb[tid] = table[tid * NH + h];

  // Q A-fragments for this wave (held in registers all kernel)
  half8 qf[2];
#pragma unroll
  for (int ks = 0; ks < 2; ks++)
    qf[ks] = *(const half8*)(Q + ((size_t)bh * S_LEN + q0 + w * 16 + l15) * DKV +
                             ks * 32 + quad * 8);

  floatx4 o[4];
  float m[4], l[4];
#pragma unroll
  for (int r = 0; r < 4; r++) { m[r] = -1e30f; l[r] = 0.0f; }
#pragma unroll
  for (int nb = 0; nb < 4; nb++) o[nb] = (floatx4){0.f, 0.f, 0.f, 0.f};

  // staging assignment: thread -> row jr, two 8-half units (ub, ub+1)
  const int jr = tid >> 2;
  const int ub = (tid & 3) * 2;

  for (int kc = 0; kc < S_LEN; kc += 64) {
    __syncthreads();  // previous chunk's MFMA reads of Ks/Vts done
    {
      const half_t* Kg = K + ((size_t)bh * S_LEN + kc + jr) * DKV + ub * 8;
      const half_t* Vg = Vt + ((size_t)bh * DKV + jr) * S_LEN + kc + ub * 8;
      half8 k0v = *(const half8*)(Kg);
      half8 k1v = *(const half8*)(Kg + 8);
      half8 v0v = *(const half8*)(Vg);
      half8 v1v = *(const half8*)(Vg + 8);
      int sw = jr & 7;
      *(half8*)&Ks[jr * 64 + ((ub + 0) ^ sw) * 8] = k0v;
      *(half8*)&Ks[jr * 64 + ((ub + 1) ^ sw) * 8] = k1v;
      *(half8*)&Vts[jr * 64 + ((ub + 0) ^ sw) * 8] = v0v;
      *(half8*)&Vts[jr * 64 + ((ub + 1) ^ sw) * 8] = v1v;
    }
    __syncthreads();

    // ---- S = Q K^T  (per wave: 16q x 64k) ----
    floatx4 s[4];
#pragma unroll
    for (int nb = 0; nb < 4; nb++) {
      s[nb] = (floatx4){0.f, 0.f, 0.f, 0.f};
      int key = nb * 16 + l15;
      int sw = key & 7;
#pragma unroll
      for (int ks = 0; ks < 2; ks++) {
        half8 bf = *(half8*)&Ks[key * 64 + ((ks * 4 + quad) ^ sw) * 8];
        s[nb] = __builtin_amdgcn_mfma_f32_16x16x32_f16(qf[ks], bf, s[nb], 0, 0, 0);
      }
    }

    // ---- bias + online softmax (C layout: row=quad*4+r, col=nb*16+l15) ----
    float al[4];
#pragma unroll
    for (int r = 0; r < 4; r++) {
      int qabs = q0 + w * 16 + quad * 4 + r;
      float sv[4];
#pragma unroll
      for (int nb = 0; nb < 4; nb++)
        sv[nb] = s[nb][r] + tb[t5_bucket((kc + nb * 16 + l15) - qabs)];
      float cm = fmaxf(fmaxf(sv[0], sv[1]), fmaxf(sv[2], sv[3]));
#pragma unroll
      for (int msk = 1; msk <= 8; msk <<= 1) cm = fmaxf(cm, __shfl_xor(cm, msk));
      float mn = fmaxf(m[r], cm);
      al[r] = __expf(m[r] - mn);
      m[r] = mn;
      float psum = 0.0f;
#pragma unroll
      for (int nb = 0; nb < 4; nb++) {
        float p = __expf(sv[nb] - mn);
        psum += p;
        Ps[(w * 16 + quad * 4 + r) * 68 + nb * 16 + l15] = (half_t)p;
      }
#pragma unroll
      for (int msk = 1; msk <= 8; msk <<= 1) psum += __shfl_xor(psum, msk);
      l[r] = l[r] * al[r] + psum;
#pragma unroll
      for (int nb = 0; nb < 4; nb++) o[nb][r] *= al[r];
    }

    // ---- O += P V  (A=P from wave-private LDS, B=Vt swizzled) ----
    half8 af[2];
#pragma unroll
    for (int ks = 0; ks < 2; ks++)
      af[ks] = *(half8*)&Ps[(w * 16 + l15) * 68 + ks * 32 + quad * 8];
#pragma unroll
    for (int nb = 0; nb < 4; nb++) {
      int dd = nb * 16 + l15;
      int sw = dd & 7;
#pragma unroll
      for (int ks = 0; ks < 2; ks++) {
        half8 bf = *(half8*)&Vts[dd * 64 + ((ks * 4 + quad) ^ sw) * 8];
        o[nb] = __builtin_amdgcn_mfma_f32_16x16x32_f16(af[ks], bf, o[nb], 0, 0, 0);
      }
    }
  }

  // ---- epilogue: X[b*S + q][h*64 + d] = o / l ----
#pragma unroll
  for (int r = 0; r < 4; r++) {
    int q = q0 + w * 16 + quad * 4 + r;
    float inv = 1.0f / l[r];
    float* dst = X + (size_t)(b * S_LEN + q) * DMODEL + h * DKV;
#pragma unroll
    for (int nb = 0; nb < 4; nb++) dst[nb * 16 + l15] = o[nb][r] * inv;
  }
}

// ---------------------------------------------------------------------------
// kernel_launch
// d_in: 0=hidden [2,2048,1024] f32, 1=w_qkv [1024,3072] f32,
//       2=w_o [1024,1024] f32, 3=rel_bias_table [32,16] f32
// d_out: attn_output (4,194,304 f32) then position_bias (67,108,864 f32)
// ws: Qh,Kh (fp16 [b,h,s,d]) + Vth (fp16 [b,h,d,s]) + X (f32 [4096,1024])
// ---------------------------------------------------------------------------
extern "C" void kernel_launch(void* const* d_in, const int* in_sizes, int n_in,
                              void* d_out, int out_size, void* d_ws, size_t ws_size,
                              hipStream_t stream) {
  const float* hidden = (const float*)d_in[0];
  const float* w_qkv = (const float*)d_in[1];
  const float* w_o = (const float*)d_in[2];
  const float* table = (const float*)d_in[3];

  float* attn_out = (float*)d_out;
  float* bias_out = (float*)d_out + 4194304;

  half_t* Qh = (half_t*)d_ws;                  // 8 MB
  half_t* Kh = Qh + 4194304;                   // 8 MB
  half_t* Vth = Kh + 4194304;                  // 8 MB
  float* Xw = (float*)(Vth + 4194304);         // 16 MB

  // 1) position_bias
  bias_kernel<<<NH * S_LEN, 256, 0, stream>>>(table, bias_out);

  // 2) QKV projection (fp32 compute, fp16 scatter epilogue; V transposed)
  sgemm128<1><<<dim3(3072 / 128, 4096 / 128), 256, 0, stream>>>(
      hidden, w_qkv, nullptr, Qh, Kh, Vth, 4096, 3072, 1024);

  // 3) fp16 MFMA flash attention -> X [4096,1024] f32
  attn_mfma<<<dim3(S_LEN / 64, BATCH * NH), 256, 0, stream>>>(Qh, Kh, Vth, table, Xw);

  // 4) output projection: [4096,1024] @ [1024,1024] -> d_out
  sgemm128<0><<<dim3(1024 / 128, 4096 / 128), 256, 0, stream>>>(
      Xw, w_o, attn_out, nullptr, nullptr, nullptr, 4096, 1024, 1024);
}

// Round 3
// 567.385 us; speedup vs baseline: 3.8334x; 1.7011x over previous
//
#include <hip/hip_runtime.h>
#include <hip/hip_bf16.h>
#include <cstdint>
#include <cstddef>

// Problem constants (T5 self-attention, B=2, S=2048, H=16, D=64, d_model=1024)
#define S_LEN 2048
#define NH 16
#define DKV 64
#define BATCH 2
#define DMODEL 1024

typedef _Float16 half_t;
typedef __attribute__((ext_vector_type(4))) _Float16 halfx4;  // 8 B
typedef __attribute__((ext_vector_type(8))) _Float16 half8;   // MFMA A/B frag (4 VGPRs)
typedef __attribute__((ext_vector_type(4))) float floatx4;    // MFMA C/D frag

// async global->LDS, 16 B per lane; LDS dest = wave-uniform base + lane*16
__device__ __forceinline__ void load_lds16(const half_t* g, half_t* l) {
  __builtin_amdgcn_global_load_lds((const __attribute__((address_space(1))) void*)g,
                                   (__attribute__((address_space(3))) void*)l, 16, 0, 0);
}

// ---------------------------------------------------------------------------
// T5 relative-position bucket — EXACT integer thresholds (ceil(8*16^(n/8))),
// verified to agree with the fp32 reference at every integer delta.
// ---------------------------------------------------------------------------
__device__ __forceinline__ int t5_bucket(int delta) {
  int base = (delta > 0) ? 16 : 0;
  int a = delta < 0 ? -delta : delta;
  int n;
  if (a < 8)       n = a;
  else if (a < 12) n = 8;
  else if (a < 16) n = 9;
  else if (a < 23) n = 10;
  else if (a < 32) n = 11;
  else if (a < 46) n = 12;
  else if (a < 64) n = 13;
  else if (a < 91) n = 14;
  else             n = 15;
  return base + n;
}

// ---------------------------------------------------------------------------
// position_bias output: out[(h*S + q)*S + k] = table[bucket(k-q)*NH + h]
// Memory-bound: 268 MB write (~43 us floor at 6.3 TB/s).
// ---------------------------------------------------------------------------
__global__ __launch_bounds__(256) void bias_kernel(const float* __restrict__ table,
                                                   float* __restrict__ out) {
  int h = blockIdx.x >> 11;
  int q = blockIdx.x & (S_LEN - 1);
  __shared__ float tb[32];
  if (threadIdx.x < 32) tb[threadIdx.x] = table[threadIdx.x * NH + h];
  __syncthreads();
  float* dst = out + (size_t)blockIdx.x * S_LEN;
  int k0 = threadIdx.x * 4;
#pragma unroll
  for (int half = 0; half < 2; half++) {
    int k = k0 + half * 1024;
    float4 v;
    v.x = tb[t5_bucket((k + 0) - q)];
    v.y = tb[t5_bucket((k + 1) - q)];
    v.z = tb[t5_bucket((k + 2) - q)];
    v.w = tb[t5_bucket((k + 3) - q)];
    *(float4*)(dst + k) = v;
  }
}

// ---------------------------------------------------------------------------
// fp32 -> fp16 flat cast (hidden_states). n4 = n/4 float4 groups, exact fit.
// ---------------------------------------------------------------------------
__global__ __launch_bounds__(256) void cast_f2h(const float* __restrict__ in,
                                                half_t* __restrict__ out) {
  int i = blockIdx.x * 256 + threadIdx.x;
  float4 v = ((const float4*)in)[i];
  halfx4 h;
  h[0] = (half_t)v.x; h[1] = (half_t)v.y; h[2] = (half_t)v.z; h[3] = (half_t)v.w;
  ((halfx4*)out)[i] = h;
}

// ---------------------------------------------------------------------------
// fp32 [R][C] -> fp16 [C][R] transpose+cast (weights). 32x32 LDS tile.
// grid = (C/32, R/32), 256 threads.
// ---------------------------------------------------------------------------
__global__ __launch_bounds__(256) void transpose_cast(const float* __restrict__ in,
                                                      half_t* __restrict__ out,
                                                      int R, int C) {
  __shared__ float t[32][33];
  int lr = threadIdx.x >> 3;        // 0..31
  int lc = (threadIdx.x & 7) * 4;   // 0..28
  int r0 = blockIdx.y * 32, c0 = blockIdx.x * 32;
  float4 v = *(const float4*)(in + (size_t)(r0 + lr) * C + c0 + lc);
  t[lr][lc + 0] = v.x; t[lr][lc + 1] = v.y; t[lr][lc + 2] = v.z; t[lr][lc + 3] = v.w;
  __syncthreads();
  halfx4 hv;
#pragma unroll
  for (int u = 0; u < 4; u++) hv[u] = (half_t)t[lc + u][lr];
  *(halfx4*)(out + (size_t)(c0 + lr) * R + r0 + lc) = hv;
}

// ---------------------------------------------------------------------------
// fp16 MFMA GEMM: C[M,N] = A[M,K] @ Bt[N,K]^T. 128x128 tile, BK=32, 256 thr
// (4 waves, 2x2), 4x4 mfma_f32_16x16x32_f16 frags per wave.
//
// LDS layout is fragment-native: per 16-row block, unit u = quad*16 + row
// (16 B units) -- so ds_read_b128 at (block_base + lane*16) yields exactly
// the MFMA A/B fragment, and staging is global_load_lds width-16 with the
// per-lane global address A[row=l15][k=quad*8..+7]. Conflict-free (2-way).
//
// MODE 0: fp32 store to C.
// MODE 1: QKV epilogue -> fp16: Q,K scatter to [b,h,s,d]; V scatter
//         transposed to Vt[b,h,d,s].
// ---------------------------------------------------------------------------
template <int MODE>
__global__ __launch_bounds__(256) void hgemm128(const half_t* __restrict__ A,
                                                const half_t* __restrict__ Bt,
                                                float* __restrict__ C,
                                                half_t* __restrict__ Qo,
                                                half_t* __restrict__ Ko,
                                                half_t* __restrict__ Vto,
                                                int M, int N, int K) {
  __shared__ half_t Asl[8 * 512];   // 8 blocks x (16 rows x 32 halves)
  __shared__ half_t Bsl[8 * 512];

  const int tid = threadIdx.x;
  const int w = tid >> 6;
  const int lane = tid & 63;
  const int l15 = lane & 15;
  const int quad = lane >> 4;
  const int wm = w >> 1, wn = w & 1;
  const int m0 = blockIdx.y * 128;
  const int n0 = blockIdx.x * 128;

  floatx4 acc[4][4];
#pragma unroll
  for (int i = 0; i < 4; i++)
#pragma unroll
    for (int j = 0; j < 4; j++) acc[i][j] = (floatx4){0.f, 0.f, 0.f, 0.f};

  // staging addresses: wave w stages A/B blocks 2w and 2w+1
  const half_t* ga0 = A + (size_t)(m0 + (2 * w + 0) * 16 + l15) * K + quad * 8;
  const half_t* ga1 = A + (size_t)(m0 + (2 * w + 1) * 16 + l15) * K + quad * 8;
  const half_t* gb0 = Bt + (size_t)(n0 + (2 * w + 0) * 16 + l15) * K + quad * 8;
  const half_t* gb1 = Bt + (size_t)(n0 + (2 * w + 1) * 16 + l15) * K + quad * 8;
  half_t* la0 = &Asl[(2 * w + 0) * 512];
  half_t* la1 = &Asl[(2 * w + 1) * 512];
  half_t* lb0 = &Bsl[(2 * w + 0) * 512];
  half_t* lb1 = &Bsl[(2 * w + 1) * 512];

  for (int k0 = 0; k0 < K; k0 += 32) {
    __syncthreads();                 // prior iter's ds_reads complete
    load_lds16(ga0 + k0, la0);
    load_lds16(ga1 + k0, la1);
    load_lds16(gb0 + k0, lb0);
    load_lds16(gb1 + k0, lb1);
    __syncthreads();                 // vmcnt(0) drain + barrier

    half8 af[4], bf[4];
#pragma unroll
    for (int i = 0; i < 4; i++) af[i] = *(half8*)&Asl[(wm * 4 + i) * 512 + lane * 8];
#pragma unroll
    for (int j = 0; j < 4; j++) bf[j] = *(half8*)&Bsl[(wn * 4 + j) * 512 + lane * 8];
#pragma unroll
    for (int i = 0; i < 4; i++)
#pragma unroll
      for (int j = 0; j < 4; j++)
        acc[i][j] = __builtin_amdgcn_mfma_f32_16x16x32_f16(af[i], bf[j], acc[i][j], 0, 0, 0);
  }

  // epilogue: lane holds D[row = i*16 + quad*4 + r][col = j*16 + l15] of the
  // wave's 64x64 sub-tile at (m0 + wm*64, n0 + wn*64).
  const int rowbase = m0 + wm * 64;
  const int colbase = n0 + wn * 64;
  if (MODE == 0) {
#pragma unroll
    for (int i = 0; i < 4; i++)
#pragma unroll
      for (int j = 0; j < 4; j++)
#pragma unroll
        for (int r = 0; r < 4; r++)
          C[(size_t)(rowbase + i * 16 + quad * 4 + r) * N + colbase + j * 16 + l15] =
              acc[i][j][r];
  } else {
    const int which = colbase >> 10;            // 0=q,1=k,2=v (uniform per wave)
    const int h = (colbase & 1023) >> 6;        // uniform per wave (64-col tile)
    const int b = rowbase >> 11;
    const int s0 = rowbase & (S_LEN - 1);
    if (which < 2) {
      half_t* base = ((which == 0) ? Qo : Ko) + (size_t)(b * NH + h) * S_LEN * DKV;
#pragma unroll
      for (int i = 0; i < 4; i++)
#pragma unroll
        for (int j = 0; j < 4; j++)
#pragma unroll
          for (int r = 0; r < 4; r++)
            base[(size_t)(s0 + i * 16 + quad * 4 + r) * DKV + j * 16 + l15] =
                (half_t)acc[i][j][r];
    } else {
      half_t* base = Vto + (size_t)(b * NH + h) * DKV * S_LEN;
#pragma unroll
      for (int i = 0; i < 4; i++)
#pragma unroll
        for (int j = 0; j < 4; j++)
#pragma unroll
          for (int r = 0; r < 4; r++)
            base[(size_t)(j * 16 + l15) * S_LEN + s0 + i * 16 + quad * 4 + r] =
                (half_t)acc[i][j][r];
    }
  }
}

// ---------------------------------------------------------------------------
// fp16 MFMA flash attention with T5 relative bias (no 1/sqrt(d) scale).
// grid = (S/64, BATCH*NH); block = 256 (4 waves). Unchanged from round 2
// except X is now stored fp16 (feeds the fp16 output-projection GEMM).
// ---------------------------------------------------------------------------
__global__ __launch_bounds__(256) void attn_mfma(const half_t* __restrict__ Q,
                                                 const half_t* __restrict__ K,
                                                 const half_t* __restrict__ Vt,
                                                 const float* __restrict__ table,
                                                 half_t* __restrict__ X) {
  __shared__ half_t Ks[64 * 64];    // [key][d] swizzled
  __shared__ half_t Vts[64 * 64];   // [d][key] swizzled
  __shared__ half_t Ps[64 * 68];    // [q][key], stride 68
  __shared__ float tb[32];

  const int tid = threadIdx.x;
  const int w = tid >> 6;
  const int lane = tid & 63;
  const int l15 = lane & 15;
  const int quad = lane >> 4;
  const int bh = blockIdx.y;
  const int h = bh & (NH - 1);
  const int b = bh >> 4;
  const int q0 = blockIdx.x * 64;

  if (tid < 32) tb[tid] = table[tid * NH + h];

  half8 qf[2];
#pragma unroll
  for (int ks = 0; ks < 2; ks++)
    qf[ks] = *(const half8*)(Q + ((size_t)bh * S_LEN + q0 + w * 16 + l15) * DKV +
                             ks * 32 + quad * 8);

  floatx4 o[4];
  float m[4], l[4];
#pragma unroll
  for (int r = 0; r < 4; r++) { m[r] = -1e30f; l[r] = 0.0f; }
#pragma unroll
  for (int nb = 0; nb < 4; nb++) o[nb] = (floatx4){0.f, 0.f, 0.f, 0.f};

  const int jr = tid >> 2;
  const int ub = (tid & 3) * 2;

  for (int kc = 0; kc < S_LEN; kc += 64) {
    __syncthreads();
    {
      const half_t* Kg = K + ((size_t)bh * S_LEN + kc + jr) * DKV + ub * 8;
      const half_t* Vg = Vt + ((size_t)bh * DKV + jr) * S_LEN + kc + ub * 8;
      half8 k0v = *(const half8*)(Kg);
      half8 k1v = *(const half8*)(Kg + 8);
      half8 v0v = *(const half8*)(Vg);
      half8 v1v = *(const half8*)(Vg + 8);
      int sw = jr & 7;
      *(half8*)&Ks[jr * 64 + ((ub + 0) ^ sw) * 8] = k0v;
      *(half8*)&Ks[jr * 64 + ((ub + 1) ^ sw) * 8] = k1v;
      *(half8*)&Vts[jr * 64 + ((ub + 0) ^ sw) * 8] = v0v;
      *(half8*)&Vts[jr * 64 + ((ub + 1) ^ sw) * 8] = v1v;
    }
    __syncthreads();

    // ---- S = Q K^T ----
    floatx4 s[4];
#pragma unroll
    for (int nb = 0; nb < 4; nb++) {
      s[nb] = (floatx4){0.f, 0.f, 0.f, 0.f};
      int key = nb * 16 + l15;
      int sw = key & 7;
#pragma unroll
      for (int ks = 0; ks < 2; ks++) {
        half8 bf = *(half8*)&Ks[key * 64 + ((ks * 4 + quad) ^ sw) * 8];
        s[nb] = __builtin_amdgcn_mfma_f32_16x16x32_f16(qf[ks], bf, s[nb], 0, 0, 0);
      }
    }

    // ---- bias + online softmax ----
    float al[4];
#pragma unroll
    for (int r = 0; r < 4; r++) {
      int qabs = q0 + w * 16 + quad * 4 + r;
      float sv[4];
#pragma unroll
      for (int nb = 0; nb < 4; nb++)
        sv[nb] = s[nb][r] + tb[t5_bucket((kc + nb * 16 + l15) - qabs)];
      float cm = fmaxf(fmaxf(sv[0], sv[1]), fmaxf(sv[2], sv[3]));
#pragma unroll
      for (int msk = 1; msk <= 8; msk <<= 1) cm = fmaxf(cm, __shfl_xor(cm, msk));
      float mn = fmaxf(m[r], cm);
      al[r] = __expf(m[r] - mn);
      m[r] = mn;
      float psum = 0.0f;
#pragma unroll
      for (int nb = 0; nb < 4; nb++) {
        float p = __expf(sv[nb] - mn);
        psum += p;
        Ps[(w * 16 + quad * 4 + r) * 68 + nb * 16 + l15] = (half_t)p;
      }
#pragma unroll
      for (int msk = 1; msk <= 8; msk <<= 1) psum += __shfl_xor(psum, msk);
      l[r] = l[r] * al[r] + psum;
#pragma unroll
      for (int nb = 0; nb < 4; nb++) o[nb][r] *= al[r];
    }

    // ---- O += P V ----
    half8 af[2];
#pragma unroll
    for (int ks = 0; ks < 2; ks++)
      af[ks] = *(half8*)&Ps[(w * 16 + l15) * 68 + ks * 32 + quad * 8];
#pragma unroll
    for (int nb = 0; nb < 4; nb++) {
      int dd = nb * 16 + l15;
      int sw = dd & 7;
#pragma unroll
      for (int ks = 0; ks < 2; ks++) {
        half8 bf = *(half8*)&Vts[dd * 64 + ((ks * 4 + quad) ^ sw) * 8];
        o[nb] = __builtin_amdgcn_mfma_f32_16x16x32_f16(af[ks], bf, o[nb], 0, 0, 0);
      }
    }
  }

  // ---- epilogue: X[b*S + q][h*64 + d] = (fp16)(o / l) ----
#pragma unroll
  for (int r = 0; r < 4; r++) {
    int q = q0 + w * 16 + quad * 4 + r;
    float inv = 1.0f / l[r];
    half_t* dst = X + (size_t)(b * S_LEN + q) * DMODEL + h * DKV;
#pragma unroll
    for (int nb = 0; nb < 4; nb++) dst[nb * 16 + l15] = (half_t)(o[nb][r] * inv);
  }
}

// ---------------------------------------------------------------------------
// kernel_launch
// d_in: 0=hidden [2,2048,1024] f32, 1=w_qkv [1024,3072] f32,
//       2=w_o [1024,1024] f32, 3=rel_bias_table [32,16] f32
// d_out: attn_output (4,194,304 f32) then position_bias (67,108,864 f32)
// ws (fp16): Ah 8MB | Wqt 6MB | Wot 2MB | Qh 8MB | Kh 8MB | Vth 8MB | Xh 8MB
// ---------------------------------------------------------------------------
extern "C" void kernel_launch(void* const* d_in, const int* in_sizes, int n_in,
                              void* d_out, int out_size, void* d_ws, size_t ws_size,
                              hipStream_t stream) {
  const float* hidden = (const float*)d_in[0];
  const float* w_qkv = (const float*)d_in[1];
  const float* w_o = (const float*)d_in[2];
  const float* table = (const float*)d_in[3];

  float* attn_out = (float*)d_out;
  float* bias_out = (float*)d_out + 4194304;

  half_t* Ah  = (half_t*)d_ws;
  half_t* Wqt = Ah + 4194304;      // [3072][1024]
  half_t* Wot = Wqt + 3145728;     // [1024][1024]
  half_t* Qh  = Wot + 1048576;     // [b,h,s,d]
  half_t* Kh  = Qh + 4194304;      // [b,h,s,d]
  half_t* Vth = Kh + 4194304;      // [b,h,d,s]
  half_t* Xh  = Vth + 4194304;     // [4096][1024]

  // prep: casts + weight transposes + position_bias
  cast_f2h<<<4096, 256, 0, stream>>>(hidden, Ah);
  transpose_cast<<<dim3(3072 / 32, 1024 / 32), 256, 0, stream>>>(w_qkv, Wqt, 1024, 3072);
  transpose_cast<<<dim3(1024 / 32, 1024 / 32), 256, 0, stream>>>(w_o, Wot, 1024, 1024);
  bias_kernel<<<NH * S_LEN, 256, 0, stream>>>(table, bias_out);

  // QKV projection (fp16 MFMA, scatter epilogue)
  hgemm128<1><<<dim3(3072 / 128, 4096 / 128), 256, 0, stream>>>(
      Ah, Wqt, nullptr, Qh, Kh, Vth, 4096, 3072, 1024);

  // fp16 MFMA flash attention -> Xh
  attn_mfma<<<dim3(S_LEN / 64, BATCH * NH), 256, 0, stream>>>(Qh, Kh, Vth, table, Xh);

  // output projection (fp16 MFMA) -> d_out fp32
  hgemm128<0><<<dim3(1024 / 128, 4096 / 128), 256, 0, stream>>>(
      Xh, Wot, attn_out, nullptr, nullptr, nullptr, 4096, 1024, 1024);
}

// Round 4
// 538.088 us; speedup vs baseline: 4.0421x; 1.0544x over previous
//
#include <hip/hip_runtime.h>
#include <hip/hip_bf16.h>
#include <cstdint>
#include <cstddef>

// Problem constants (T5 self-attention, B=2, S=2048, H=16, D=64, d_model=1024)
#define S_LEN 2048
#define NH 16
#define DKV 64
#define BATCH 2
#define DMODEL 1024

typedef _Float16 half_t;
typedef __attribute__((ext_vector_type(4))) _Float16 halfx4;  // 8 B
typedef __attribute__((ext_vector_type(8))) _Float16 half8;   // MFMA A/B frag (4 VGPRs)
typedef __attribute__((ext_vector_type(4))) float floatx4;    // MFMA C/D frag

// async global->LDS, 16 B per lane; LDS dest = wave-uniform base + lane*16
__device__ __forceinline__ void load_lds16(const half_t* g, half_t* l) {
  __builtin_amdgcn_global_load_lds((const __attribute__((address_space(1))) void*)g,
                                   (__attribute__((address_space(3))) void*)l, 16, 0, 0);
}

// ---------------------------------------------------------------------------
// T5 relative-position bucket — EXACT integer thresholds (ceil(8*16^(n/8))),
// verified to agree with the fp32 reference at every integer delta.
// Capped for |delta| >= 91 (bucket 15 / 31) -> 183-entry table covers all.
// ---------------------------------------------------------------------------
__device__ __forceinline__ int t5_bucket(int delta) {
  int base = (delta > 0) ? 16 : 0;
  int a = delta < 0 ? -delta : delta;
  int n;
  if (a < 8)       n = a;
  else if (a < 12) n = 8;
  else if (a < 16) n = 9;
  else if (a < 23) n = 10;
  else if (a < 32) n = 11;
  else if (a < 46) n = 12;
  else if (a < 64) n = 13;
  else if (a < 91) n = 14;
  else             n = 15;
  return base + n;
}

// ---------------------------------------------------------------------------
// position_bias output: out[(h*S + q)*S + k] = table[bucket(k-q)*NH + h]
// Memory-bound: 268 MB write (~43 us floor at 6.3 TB/s).
// ---------------------------------------------------------------------------
__global__ __launch_bounds__(256) void bias_kernel(const float* __restrict__ table,
                                                   float* __restrict__ out) {
  int h = blockIdx.x >> 11;
  int q = blockIdx.x & (S_LEN - 1);
  __shared__ float tb[32];
  if (threadIdx.x < 32) tb[threadIdx.x] = table[threadIdx.x * NH + h];
  __syncthreads();
  float* dst = out + (size_t)blockIdx.x * S_LEN;
  int k0 = threadIdx.x * 4;
#pragma unroll
  for (int half = 0; half < 2; half++) {
    int k = k0 + half * 1024;
    float4 v;
    v.x = tb[t5_bucket((k + 0) - q)];
    v.y = tb[t5_bucket((k + 1) - q)];
    v.z = tb[t5_bucket((k + 2) - q)];
    v.w = tb[t5_bucket((k + 3) - q)];
    *(float4*)(dst + k) = v;
  }
}

// ---------------------------------------------------------------------------
// fp32 -> fp16 flat cast (hidden_states).
// ---------------------------------------------------------------------------
__global__ __launch_bounds__(256) void cast_f2h(const float* __restrict__ in,
                                                half_t* __restrict__ out) {
  int i = blockIdx.x * 256 + threadIdx.x;
  float4 v = ((const float4*)in)[i];
  halfx4 h;
  h[0] = (half_t)v.x; h[1] = (half_t)v.y; h[2] = (half_t)v.z; h[3] = (half_t)v.w;
  ((halfx4*)out)[i] = h;
}

// ---------------------------------------------------------------------------
// fp32 [R][C] -> fp16 [C][R] transpose+cast (weights). 32x32 LDS tile.
// ---------------------------------------------------------------------------
__global__ __launch_bounds__(256) void transpose_cast(const float* __restrict__ in,
                                                      half_t* __restrict__ out,
                                                      int R, int C) {
  __shared__ float t[32][33];
  int lr = threadIdx.x >> 3;
  int lc = (threadIdx.x & 7) * 4;
  int r0 = blockIdx.y * 32, c0 = blockIdx.x * 32;
  float4 v = *(const float4*)(in + (size_t)(r0 + lr) * C + c0 + lc);
  t[lr][lc + 0] = v.x; t[lr][lc + 1] = v.y; t[lr][lc + 2] = v.z; t[lr][lc + 3] = v.w;
  __syncthreads();
  halfx4 hv;
#pragma unroll
  for (int u = 0; u < 4; u++) hv[u] = (half_t)t[lc + u][lr];
  *(halfx4*)(out + (size_t)(c0 + lr) * R + r0 + lc) = hv;
}

// ---------------------------------------------------------------------------
// fp16 [b,h,s,d] -> [b,h,d,s] transpose (V). 64x64 tile per block.
// grid = (S/64, BATCH*NH), 256 threads. Coalesced 16B loads/stores;
// transpose via LDS (stride 72 halves breaks conflicts on b16 writes).
// ---------------------------------------------------------------------------
__global__ __launch_bounds__(256) void vtrans(const half_t* __restrict__ V,
                                              half_t* __restrict__ Vt) {
  __shared__ half_t T[64 * 72];
  const int bh = blockIdx.y;
  const int s0 = blockIdx.x * 64;
  const half_t* src = V + ((size_t)bh * S_LEN + s0) * DKV;
  half_t* dst = Vt + (size_t)bh * DKV * S_LEN + s0;
  const int sr = threadIdx.x >> 3;        // 0..31
  const int dc = (threadIdx.x & 7) * 8;   // 0..56
#pragma unroll
  for (int p = 0; p < 2; p++) {
    int s = sr + p * 32;
    half8 v = *(const half8*)(src + (size_t)s * DKV + dc);
#pragma unroll
    for (int u = 0; u < 8; u++) T[(dc + u) * 72 + s] = v[u];
  }
  __syncthreads();
#pragma unroll
  for (int p = 0; p < 2; p++) {
    int d = sr + p * 32;
    half8 v = *(half8*)&T[d * 72 + dc];
    *(half8*)(dst + (size_t)d * S_LEN + dc) = v;
  }
}

// ---------------------------------------------------------------------------
// fp16 MFMA GEMM: C[M,N] = A[M,K] @ Bt[N,K]^T. 128x128 tile, BK=32, 256 thr
// (4 waves, 2x2), 4x4 mfma_f32_16x16x32_f16 frags per wave.
// LDS layout fragment-native; staging via global_load_lds width-16.
// MODE 0: fp32 store to C.
// MODE 1: QKV epilogue -> fp16: Q,K,V all scattered to [b,h,s,d] (coalesced
//         within rows; V transposed later by vtrans).
// ---------------------------------------------------------------------------
template <int MODE>
__global__ __launch_bounds__(256) void hgemm128(const half_t* __restrict__ A,
                                                const half_t* __restrict__ Bt,
                                                float* __restrict__ C,
                                                half_t* __restrict__ Qo,
                                                half_t* __restrict__ Ko,
                                                half_t* __restrict__ Vo,
                                                int M, int N, int K) {
  __shared__ half_t Asl[8 * 512];
  __shared__ half_t Bsl[8 * 512];

  const int tid = threadIdx.x;
  const int w = tid >> 6;
  const int lane = tid & 63;
  const int l15 = lane & 15;
  const int quad = lane >> 4;
  const int wm = w >> 1, wn = w & 1;
  const int m0 = blockIdx.y * 128;
  const int n0 = blockIdx.x * 128;

  floatx4 acc[4][4];
#pragma unroll
  for (int i = 0; i < 4; i++)
#pragma unroll
    for (int j = 0; j < 4; j++) acc[i][j] = (floatx4){0.f, 0.f, 0.f, 0.f};

  const half_t* ga0 = A + (size_t)(m0 + (2 * w + 0) * 16 + l15) * K + quad * 8;
  const half_t* ga1 = A + (size_t)(m0 + (2 * w + 1) * 16 + l15) * K + quad * 8;
  const half_t* gb0 = Bt + (size_t)(n0 + (2 * w + 0) * 16 + l15) * K + quad * 8;
  const half_t* gb1 = Bt + (size_t)(n0 + (2 * w + 1) * 16 + l15) * K + quad * 8;
  half_t* la0 = &Asl[(2 * w + 0) * 512];
  half_t* la1 = &Asl[(2 * w + 1) * 512];
  half_t* lb0 = &Bsl[(2 * w + 0) * 512];
  half_t* lb1 = &Bsl[(2 * w + 1) * 512];

  for (int k0 = 0; k0 < K; k0 += 32) {
    __syncthreads();
    load_lds16(ga0 + k0, la0);
    load_lds16(ga1 + k0, la1);
    load_lds16(gb0 + k0, lb0);
    load_lds16(gb1 + k0, lb1);
    __syncthreads();

    half8 af[4], bf[4];
#pragma unroll
    for (int i = 0; i < 4; i++) af[i] = *(half8*)&Asl[(wm * 4 + i) * 512 + lane * 8];
#pragma unroll
    for (int j = 0; j < 4; j++) bf[j] = *(half8*)&Bsl[(wn * 4 + j) * 512 + lane * 8];
#pragma unroll
    for (int i = 0; i < 4; i++)
#pragma unroll
      for (int j = 0; j < 4; j++)
        acc[i][j] = __builtin_amdgcn_mfma_f32_16x16x32_f16(af[i], bf[j], acc[i][j], 0, 0, 0);
  }

  const int rowbase = m0 + wm * 64;
  const int colbase = n0 + wn * 64;
  if (MODE == 0) {
#pragma unroll
    for (int i = 0; i < 4; i++)
#pragma unroll
      for (int j = 0; j < 4; j++)
#pragma unroll
        for (int r = 0; r < 4; r++)
          C[(size_t)(rowbase + i * 16 + quad * 4 + r) * N + colbase + j * 16 + l15] =
              acc[i][j][r];
  } else {
    const int which = colbase >> 10;            // 0=q,1=k,2=v (uniform per wave)
    const int h = (colbase & 1023) >> 6;        // uniform per wave
    const int b = rowbase >> 11;
    const int s0 = rowbase & (S_LEN - 1);
    half_t* base = ((which == 0) ? Qo : (which == 1) ? Ko : Vo) +
                   (size_t)(b * NH + h) * S_LEN * DKV;
#pragma unroll
    for (int i = 0; i < 4; i++)
#pragma unroll
      for (int j = 0; j < 4; j++)
#pragma unroll
        for (int r = 0; r < 4; r++)
          base[(size_t)(s0 + i * 16 + quad * 4 + r) * DKV + j * 16 + l15] =
              (half_t)acc[i][j][r];
  }
}

// ---------------------------------------------------------------------------
// fp16 MFMA flash attention with T5 relative bias (no 1/sqrt(d) scale).
// grid = (S/64, BATCH*NH); block = 256 (4 waves).
//
// Bias applied MULTIPLICATIVELY after exp: exp(s+bias-m) = exp(s-m)*exp(bias),
// with exp(bias) from a 183-entry LDS table (bucket(delta) constant for
// |delta|>=91). Running max over raw s only -> p <= exp(max bias) ~ 55,
// safely in fp16 range; fp16 relative precision unchanged.
// ---------------------------------------------------------------------------
__global__ __launch_bounds__(256) void attn_mfma(const half_t* __restrict__ Q,
                                                 const half_t* __restrict__ K,
                                                 const half_t* __restrict__ Vt,
                                                 const float* __restrict__ table,
                                                 half_t* __restrict__ X) {
  __shared__ half_t Ks[64 * 64];    // [key][d] swizzled
  __shared__ half_t Vts[64 * 64];   // [d][key] swizzled
  __shared__ half_t Ps[64 * 68];    // [q][key], stride 68
  __shared__ float tb[32];
  __shared__ float ebias[184];      // exp(bias) by clamp(delta,-91,91)+91

  const int tid = threadIdx.x;
  const int w = tid >> 6;
  const int lane = tid & 63;
  const int l15 = lane & 15;
  const int quad = lane >> 4;
  const int bh = blockIdx.y;
  const int h = bh & (NH - 1);
  const int b = bh >> 4;
  const int q0 = blockIdx.x * 64;

  if (tid < 32) tb[tid] = table[tid * NH + h];
  __syncthreads();
  if (tid < 183) ebias[tid] = __expf(tb[t5_bucket(tid - 91)]);

  half8 qf[2];
#pragma unroll
  for (int ks = 0; ks < 2; ks++)
    qf[ks] = *(const half8*)(Q + ((size_t)bh * S_LEN + q0 + w * 16 + l15) * DKV +
                             ks * 32 + quad * 8);

  floatx4 o[4];
  float m[4], l[4];
#pragma unroll
  for (int r = 0; r < 4; r++) { m[r] = -1e30f; l[r] = 0.0f; }
#pragma unroll
  for (int nb = 0; nb < 4; nb++) o[nb] = (floatx4){0.f, 0.f, 0.f, 0.f};

  const int jr = tid >> 2;
  const int ub = (tid & 3) * 2;

  for (int kc = 0; kc < S_LEN; kc += 64) {
    __syncthreads();   // prior chunk's reads done (also publishes ebias on iter 0)
    {
      const half_t* Kg = K + ((size_t)bh * S_LEN + kc + jr) * DKV + ub * 8;
      const half_t* Vg = Vt + ((size_t)bh * DKV + jr) * S_LEN + kc + ub * 8;
      half8 k0v = *(const half8*)(Kg);
      half8 k1v = *(const half8*)(Kg + 8);
      half8 v0v = *(const half8*)(Vg);
      half8 v1v = *(const half8*)(Vg + 8);
      int sw = jr & 7;
      *(half8*)&Ks[jr * 64 + ((ub + 0) ^ sw) * 8] = k0v;
      *(half8*)&Ks[jr * 64 + ((ub + 1) ^ sw) * 8] = k1v;
      *(half8*)&Vts[jr * 64 + ((ub + 0) ^ sw) * 8] = v0v;
      *(half8*)&Vts[jr * 64 + ((ub + 1) ^ sw) * 8] = v1v;
    }
    __syncthreads();

    // ---- S = Q K^T ----
    floatx4 s[4];
#pragma unroll
    for (int nb = 0; nb < 4; nb++) {
      s[nb] = (floatx4){0.f, 0.f, 0.f, 0.f};
      int key = nb * 16 + l15;
      int sw = key & 7;
#pragma unroll
      for (int ks = 0; ks < 2; ks++) {
        half8 bf = *(half8*)&Ks[key * 64 + ((ks * 4 + quad) ^ sw) * 8];
        s[nb] = __builtin_amdgcn_mfma_f32_16x16x32_f16(qf[ks], bf, s[nb], 0, 0, 0);
      }
    }

    // ---- online softmax (max over raw s; bias applied as exp(bias) factor) ----
    float al[4];
#pragma unroll
    for (int r = 0; r < 4; r++) {
      int qabs = q0 + w * 16 + quad * 4 + r;
      int db = kc + l15 - qabs + 91;   // delta+91 at nb=0
      float cm = fmaxf(fmaxf(s[0][r], s[1][r]), fmaxf(s[2][r], s[3][r]));
#pragma unroll
      for (int msk = 1; msk <= 8; msk <<= 1) cm = fmaxf(cm, __shfl_xor(cm, msk));
      float mn = fmaxf(m[r], cm);
      al[r] = __expf(m[r] - mn);
      m[r] = mn;
      float psum = 0.0f;
#pragma unroll
      for (int nb = 0; nb < 4; nb++) {
        int idx = db + nb * 16;
        idx = idx < 0 ? 0 : (idx > 182 ? 182 : idx);   // v_med3-style clamp
        float p = __expf(s[nb][r] - mn) * ebias[idx];
        psum += p;
        Ps[(w * 16 + quad * 4 + r) * 68 + nb * 16 + l15] = (half_t)p;
      }
#pragma unroll
      for (int msk = 1; msk <= 8; msk <<= 1) psum += __shfl_xor(psum, msk);
      l[r] = l[r] * al[r] + psum;
#pragma unroll
      for (int nb = 0; nb < 4; nb++) o[nb][r] *= al[r];
    }

    // ---- O += P V ----
    half8 af[2];
#pragma unroll
    for (int ks = 0; ks < 2; ks++)
      af[ks] = *(half8*)&Ps[(w * 16 + l15) * 68 + ks * 32 + quad * 8];
#pragma unroll
    for (int nb = 0; nb < 4; nb++) {
      int dd = nb * 16 + l15;
      int sw = dd & 7;
#pragma unroll
      for (int ks = 0; ks < 2; ks++) {
        half8 bf = *(half8*)&Vts[dd * 64 + ((ks * 4 + quad) ^ sw) * 8];
        o[nb] = __builtin_amdgcn_mfma_f32_16x16x32_f16(af[ks], bf, o[nb], 0, 0, 0);
      }
    }
  }

  // ---- epilogue: X[b*S + q][h*64 + d] = (fp16)(o / l) ----
#pragma unroll
  for (int r = 0; r < 4; r++) {
    int q = q0 + w * 16 + quad * 4 + r;
    float inv = 1.0f / l[r];
    half_t* dst = X + (size_t)(b * S_LEN + q) * DMODEL + h * DKV;
#pragma unroll
    for (int nb = 0; nb < 4; nb++) dst[nb * 16 + l15] = (half_t)(o[nb][r] * inv);
  }
}

// ---------------------------------------------------------------------------
// kernel_launch
// ws (fp16 halves): Ah 4M (reused as Vt after hgemm1) | Wqt 3M | Wot 1M |
//                   Qh 4M | Kh 4M | Vh 4M | Xh 4M  = 24M halves = 48 MB
// ---------------------------------------------------------------------------
extern "C" void kernel_launch(void* const* d_in, const int* in_sizes, int n_in,
                              void* d_out, int out_size, void* d_ws, size_t ws_size,
                              hipStream_t stream) {
  const float* hidden = (const float*)d_in[0];
  const float* w_qkv = (const float*)d_in[1];
  const float* w_o = (const float*)d_in[2];
  const float* table = (const float*)d_in[3];

  float* attn_out = (float*)d_out;
  float* bias_out = (float*)d_out + 4194304;

  half_t* Ah  = (half_t*)d_ws;     // hidden fp16; reused as Vt after hgemm1
  half_t* Wqt = Ah + 4194304;      // [3072][1024]
  half_t* Wot = Wqt + 3145728;     // [1024][1024]
  half_t* Qh  = Wot + 1048576;     // [b,h,s,d]
  half_t* Kh  = Qh + 4194304;      // [b,h,s,d]
  half_t* Vh  = Kh + 4194304;      // [b,h,s,d]
  half_t* Xh  = Vh + 4194304;      // [4096][1024]
  half_t* Vth = Ah;                // [b,h,d,s] (aliases Ah; Ah dead by then)

  // prep: casts + weight transposes + position_bias
  cast_f2h<<<4096, 256, 0, stream>>>(hidden, Ah);
  transpose_cast<<<dim3(3072 / 32, 1024 / 32), 256, 0, stream>>>(w_qkv, Wqt, 1024, 3072);
  transpose_cast<<<dim3(1024 / 32, 1024 / 32), 256, 0, stream>>>(w_o, Wot, 1024, 1024);
  bias_kernel<<<NH * S_LEN, 256, 0, stream>>>(table, bias_out);

  // QKV projection (fp16 MFMA, coalesced scatter epilogue)
  hgemm128<1><<<dim3(3072 / 128, 4096 / 128), 256, 0, stream>>>(
      Ah, Wqt, nullptr, Qh, Kh, Vh, 4096, 3072, 1024);

  // V -> Vt transpose (Ah is dead now; Vt aliases it)
  vtrans<<<dim3(S_LEN / 64, BATCH * NH), 256, 0, stream>>>(Vh, Vth);

  // fp16 MFMA flash attention -> Xh
  attn_mfma<<<dim3(S_LEN / 64, BATCH * NH), 256, 0, stream>>>(Qh, Kh, Vth, table, Xh);

  // output projection (fp16 MFMA) -> d_out fp32
  hgemm128<0><<<dim3(1024 / 128, 4096 / 128), 256, 0, stream>>>(
      Xh, Wot, attn_out, nullptr, nullptr, nullptr, 4096, 1024, 1024);
}

// Round 5
// 525.288 us; speedup vs baseline: 4.1406x; 1.0244x over previous
//
#include <hip/hip_runtime.h>
#include <hip/hip_bf16.h>
#include <cstdint>
#include <cstddef>

// Problem constants (T5 self-attention, B=2, S=2048, H=16, D=64, d_model=1024)
#define S_LEN 2048
#define NH 16
#define DKV 64
#define BATCH 2
#define DMODEL 1024

typedef _Float16 half_t;
typedef __attribute__((ext_vector_type(4))) _Float16 halfx4;  // 8 B
typedef __attribute__((ext_vector_type(8))) _Float16 half8;   // MFMA A/B frag (4 VGPRs)
typedef __attribute__((ext_vector_type(4))) float floatx4;    // MFMA C/D frag

// async global->LDS, 16 B per lane; LDS dest = wave-uniform base + lane*16
__device__ __forceinline__ void load_lds16(const half_t* g, half_t* l) {
  __builtin_amdgcn_global_load_lds((const __attribute__((address_space(1))) void*)g,
                                   (__attribute__((address_space(3))) void*)l, 16, 0, 0);
}

// ---------------------------------------------------------------------------
// T5 relative-position bucket — EXACT integer thresholds (ceil(8*16^(n/8))),
// verified to agree with the fp32 reference at every integer delta.
// Capped for |delta| >= 91 (bucket 15 / 31) -> 183-entry table covers all.
// ---------------------------------------------------------------------------
__device__ __forceinline__ int t5_bucket(int delta) {
  int base = (delta > 0) ? 16 : 0;
  int a = delta < 0 ? -delta : delta;
  int n;
  if (a < 8)       n = a;
  else if (a < 12) n = 8;
  else if (a < 16) n = 9;
  else if (a < 23) n = 10;
  else if (a < 32) n = 11;
  else if (a < 46) n = 12;
  else if (a < 64) n = 13;
  else if (a < 91) n = 14;
  else             n = 15;
  return base + n;
}

// ---------------------------------------------------------------------------
// position_bias output: out[(h*S + q)*S + k] = table[bucket(k-q)*NH + h]
// Memory-bound: 268 MB write (~43 us floor at 6.3 TB/s).
// ---------------------------------------------------------------------------
__global__ __launch_bounds__(256) void bias_kernel(const float* __restrict__ table,
                                                   float* __restrict__ out) {
  int h = blockIdx.x >> 11;
  int q = blockIdx.x & (S_LEN - 1);
  __shared__ float tb[32];
  if (threadIdx.x < 32) tb[threadIdx.x] = table[threadIdx.x * NH + h];
  __syncthreads();
  float* dst = out + (size_t)blockIdx.x * S_LEN;
  int k0 = threadIdx.x * 4;
#pragma unroll
  for (int half = 0; half < 2; half++) {
    int k = k0 + half * 1024;
    float4 v;
    v.x = tb[t5_bucket((k + 0) - q)];
    v.y = tb[t5_bucket((k + 1) - q)];
    v.z = tb[t5_bucket((k + 2) - q)];
    v.w = tb[t5_bucket((k + 3) - q)];
    *(float4*)(dst + k) = v;
  }
}

// ---------------------------------------------------------------------------
// fp32 -> fp16 flat cast (hidden_states).
// ---------------------------------------------------------------------------
__global__ __launch_bounds__(256) void cast_f2h(const float* __restrict__ in,
                                                half_t* __restrict__ out) {
  int i = blockIdx.x * 256 + threadIdx.x;
  float4 v = ((const float4*)in)[i];
  halfx4 h;
  h[0] = (half_t)v.x; h[1] = (half_t)v.y; h[2] = (half_t)v.z; h[3] = (half_t)v.w;
  ((halfx4*)out)[i] = h;
}

// ---------------------------------------------------------------------------
// fp32 [R][C] -> fp16 [C][R] transpose+cast (weights). 32x32 LDS tile.
// ---------------------------------------------------------------------------
__global__ __launch_bounds__(256) void transpose_cast(const float* __restrict__ in,
                                                      half_t* __restrict__ out,
                                                      int R, int C) {
  __shared__ float t[32][33];
  int lr = threadIdx.x >> 3;
  int lc = (threadIdx.x & 7) * 4;
  int r0 = blockIdx.y * 32, c0 = blockIdx.x * 32;
  float4 v = *(const float4*)(in + (size_t)(r0 + lr) * C + c0 + lc);
  t[lr][lc + 0] = v.x; t[lr][lc + 1] = v.y; t[lr][lc + 2] = v.z; t[lr][lc + 3] = v.w;
  __syncthreads();
  halfx4 hv;
#pragma unroll
  for (int u = 0; u < 4; u++) hv[u] = (half_t)t[lc + u][lr];
  *(halfx4*)(out + (size_t)(c0 + lr) * R + r0 + lc) = hv;
}

// ---------------------------------------------------------------------------
// fp16 [b,h,s,d] -> [b,h,d,s] transpose (V). 64x64 tile per block.
// ---------------------------------------------------------------------------
__global__ __launch_bounds__(256) void vtrans(const half_t* __restrict__ V,
                                              half_t* __restrict__ Vt) {
  __shared__ half_t T[64 * 72];
  const int bh = blockIdx.y;
  const int s0 = blockIdx.x * 64;
  const half_t* src = V + ((size_t)bh * S_LEN + s0) * DKV;
  half_t* dst = Vt + (size_t)bh * DKV * S_LEN + s0;
  const int sr = threadIdx.x >> 3;        // 0..31
  const int dc = (threadIdx.x & 7) * 8;   // 0..56
#pragma unroll
  for (int p = 0; p < 2; p++) {
    int s = sr + p * 32;
    half8 v = *(const half8*)(src + (size_t)s * DKV + dc);
#pragma unroll
    for (int u = 0; u < 8; u++) T[(dc + u) * 72 + s] = v[u];
  }
  __syncthreads();
#pragma unroll
  for (int p = 0; p < 2; p++) {
    int d = sr + p * 32;
    half8 v = *(half8*)&T[d * 72 + dc];
    *(half8*)(dst + (size_t)d * S_LEN + dc) = v;
  }
}

// ---------------------------------------------------------------------------
// fp16 MFMA GEMM: C[M,N] = A[M,K] @ Bt[N,K]^T. 128x128 tile, BK=32, 256 thr
// (4 waves, 2x2), 4x4 mfma_f32_16x16x32_f16 frags per wave.
// MODE 0: fp32 store to C.   MODE 1: QKV scatter epilogue -> fp16 [b,h,s,d].
// ---------------------------------------------------------------------------
template <int MODE>
__global__ __launch_bounds__(256) void hgemm128(const half_t* __restrict__ A,
                                                const half_t* __restrict__ Bt,
                                                float* __restrict__ C,
                                                half_t* __restrict__ Qo,
                                                half_t* __restrict__ Ko,
                                                half_t* __restrict__ Vo,
                                                int M, int N, int K) {
  __shared__ half_t Asl[8 * 512];
  __shared__ half_t Bsl[8 * 512];

  const int tid = threadIdx.x;
  const int w = tid >> 6;
  const int lane = tid & 63;
  const int l15 = lane & 15;
  const int quad = lane >> 4;
  const int wm = w >> 1, wn = w & 1;
  const int m0 = blockIdx.y * 128;
  const int n0 = blockIdx.x * 128;

  floatx4 acc[4][4];
#pragma unroll
  for (int i = 0; i < 4; i++)
#pragma unroll
    for (int j = 0; j < 4; j++) acc[i][j] = (floatx4){0.f, 0.f, 0.f, 0.f};

  const half_t* ga0 = A + (size_t)(m0 + (2 * w + 0) * 16 + l15) * K + quad * 8;
  const half_t* ga1 = A + (size_t)(m0 + (2 * w + 1) * 16 + l15) * K + quad * 8;
  const half_t* gb0 = Bt + (size_t)(n0 + (2 * w + 0) * 16 + l15) * K + quad * 8;
  const half_t* gb1 = Bt + (size_t)(n0 + (2 * w + 1) * 16 + l15) * K + quad * 8;
  half_t* la0 = &Asl[(2 * w + 0) * 512];
  half_t* la1 = &Asl[(2 * w + 1) * 512];
  half_t* lb0 = &Bsl[(2 * w + 0) * 512];
  half_t* lb1 = &Bsl[(2 * w + 1) * 512];

  for (int k0 = 0; k0 < K; k0 += 32) {
    __syncthreads();
    load_lds16(ga0 + k0, la0);
    load_lds16(ga1 + k0, la1);
    load_lds16(gb0 + k0, lb0);
    load_lds16(gb1 + k0, lb1);
    __syncthreads();

    half8 af[4], bf[4];
#pragma unroll
    for (int i = 0; i < 4; i++) af[i] = *(half8*)&Asl[(wm * 4 + i) * 512 + lane * 8];
#pragma unroll
    for (int j = 0; j < 4; j++) bf[j] = *(half8*)&Bsl[(wn * 4 + j) * 512 + lane * 8];
#pragma unroll
    for (int i = 0; i < 4; i++)
#pragma unroll
      for (int j = 0; j < 4; j++)
        acc[i][j] = __builtin_amdgcn_mfma_f32_16x16x32_f16(af[i], bf[j], acc[i][j], 0, 0, 0);
  }

  const int rowbase = m0 + wm * 64;
  const int colbase = n0 + wn * 64;
  if (MODE == 0) {
#pragma unroll
    for (int i = 0; i < 4; i++)
#pragma unroll
      for (int j = 0; j < 4; j++)
#pragma unroll
        for (int r = 0; r < 4; r++)
          C[(size_t)(rowbase + i * 16 + quad * 4 + r) * N + colbase + j * 16 + l15] =
              acc[i][j][r];
  } else {
    const int which = colbase >> 10;            // 0=q,1=k,2=v (uniform per wave)
    const int h = (colbase & 1023) >> 6;        // uniform per wave
    const int b = rowbase >> 11;
    const int s0 = rowbase & (S_LEN - 1);
    half_t* base = ((which == 0) ? Qo : (which == 1) ? Ko : Vo) +
                   (size_t)(b * NH + h) * S_LEN * DKV;
#pragma unroll
    for (int i = 0; i < 4; i++)
#pragma unroll
      for (int j = 0; j < 4; j++)
#pragma unroll
        for (int r = 0; r < 4; r++)
          base[(size_t)(s0 + i * 16 + quad * 4 + r) * DKV + j * 16 + l15] =
              (half_t)acc[i][j][r];
  }
}

// ---------------------------------------------------------------------------
// fp16 MFMA flash attention, SPLIT-K over the key axis (2 partitions of 1024).
// grid.x = (S/64)*2: qb = x>>1, part = x&1. grid.y = BATCH*NH. 4 waves/block.
// Emits UNNORMALIZED partials: Opart[part][bh][q][d] (f32), Mp/Lp[part][bh*S+q].
//
// Bias applied multiplicatively: exp(s+bias-m) = exp(s-m)*ebias[clamp(delta)].
// Wave-uniform fast path when the whole 64-key chunk is in the capped region
// (|delta|>=91 for all (q,k) of the wave): ebias is one scalar, hoisted.
// ---------------------------------------------------------------------------
__global__ __launch_bounds__(256) void attn_split(const half_t* __restrict__ Q,
                                                  const half_t* __restrict__ K,
                                                  const half_t* __restrict__ Vt,
                                                  const float* __restrict__ table,
                                                  float* __restrict__ Opart,
                                                  float* __restrict__ Mp,
                                                  float* __restrict__ Lp) {
  __shared__ half_t Ks[64 * 64];    // [key][d] swizzled
  __shared__ half_t Vts[64 * 64];   // [d][key] swizzled
  __shared__ half_t Ps[64 * 68];    // [q][key], stride 68
  __shared__ float tb[32];
  __shared__ float ebias[184];      // exp(bias) by clamp(delta,-91,91)+91

  const int tid = threadIdx.x;
  const int w = tid >> 6;
  const int lane = tid & 63;
  const int l15 = lane & 15;
  const int quad = lane >> 4;
  const int bh = blockIdx.y;
  const int h = bh & (NH - 1);
  const int part = blockIdx.x & 1;
  const int q0 = (blockIdx.x >> 1) * 64;
  const int q0w = q0 + w * 16;

  if (tid < 32) tb[tid] = table[tid * NH + h];
  __syncthreads();
  if (tid < 183) ebias[tid] = __expf(tb[t5_bucket(tid - 91)]);

  half8 qf[2];
#pragma unroll
  for (int ks = 0; ks < 2; ks++)
    qf[ks] = *(const half8*)(Q + ((size_t)bh * S_LEN + q0w + l15) * DKV +
                             ks * 32 + quad * 8);

  floatx4 o[4];
  float m[4], l[4];
#pragma unroll
  for (int r = 0; r < 4; r++) { m[r] = -1e30f; l[r] = 0.0f; }
#pragma unroll
  for (int nb = 0; nb < 4; nb++) o[nb] = (floatx4){0.f, 0.f, 0.f, 0.f};

  const int jr = tid >> 2;
  const int ub = (tid & 3) * 2;
  const int kbase = part * 1024;

  for (int kc = kbase; kc < kbase + 1024; kc += 64) {
    __syncthreads();   // prior chunk's reads done (also publishes ebias on iter 0)
    {
      const half_t* Kg = K + ((size_t)bh * S_LEN + kc + jr) * DKV + ub * 8;
      const half_t* Vg = Vt + ((size_t)bh * DKV + jr) * S_LEN + kc + ub * 8;
      half8 k0v = *(const half8*)(Kg);
      half8 k1v = *(const half8*)(Kg + 8);
      half8 v0v = *(const half8*)(Vg);
      half8 v1v = *(const half8*)(Vg + 8);
      int sw = jr & 7;
      *(half8*)&Ks[jr * 64 + ((ub + 0) ^ sw) * 8] = k0v;
      *(half8*)&Ks[jr * 64 + ((ub + 1) ^ sw) * 8] = k1v;
      *(half8*)&Vts[jr * 64 + ((ub + 0) ^ sw) * 8] = v0v;
      *(half8*)&Vts[jr * 64 + ((ub + 1) ^ sw) * 8] = v1v;
    }
    __syncthreads();

    // ---- S = Q K^T ----
    floatx4 s[4];
#pragma unroll
    for (int nb = 0; nb < 4; nb++) {
      s[nb] = (floatx4){0.f, 0.f, 0.f, 0.f};
      int key = nb * 16 + l15;
      int sw = key & 7;
#pragma unroll
      for (int ks = 0; ks < 2; ks++) {
        half8 bf = *(half8*)&Ks[key * 64 + ((ks * 4 + quad) ^ sw) * 8];
        s[nb] = __builtin_amdgcn_mfma_f32_16x16x32_f16(qf[ks], bf, s[nb], 0, 0, 0);
      }
    }

    // ---- online softmax ----
    const int rel = kc - q0w;   // wave-uniform
    float al[4];
    if (rel >= 106 || rel <= -154) {
      // whole chunk capped: single bias factor for every element
      const float eb = ebias[rel >= 106 ? 182 : 0];
#pragma unroll
      for (int r = 0; r < 4; r++) {
        float cm = fmaxf(fmaxf(s[0][r], s[1][r]), fmaxf(s[2][r], s[3][r]));
#pragma unroll
        for (int msk = 1; msk <= 8; msk <<= 1) cm = fmaxf(cm, __shfl_xor(cm, msk));
        float mn = fmaxf(m[r], cm);
        al[r] = __expf(m[r] - mn);
        m[r] = mn;
        float psum = 0.0f;
#pragma unroll
        for (int nb = 0; nb < 4; nb++) {
          float p = __expf(s[nb][r] - mn) * eb;
          psum += p;
          Ps[(w * 16 + quad * 4 + r) * 68 + nb * 16 + l15] = (half_t)p;
        }
#pragma unroll
        for (int msk = 1; msk <= 8; msk <<= 1) psum += __shfl_xor(psum, msk);
        l[r] = l[r] * al[r] + psum;
#pragma unroll
        for (int nb = 0; nb < 4; nb++) o[nb][r] *= al[r];
      }
    } else {
#pragma unroll
      for (int r = 0; r < 4; r++) {
        int qabs = q0w + quad * 4 + r;
        int db = kc + l15 - qabs + 91;   // delta+91 at nb=0
        float cm = fmaxf(fmaxf(s[0][r], s[1][r]), fmaxf(s[2][r], s[3][r]));
#pragma unroll
        for (int msk = 1; msk <= 8; msk <<= 1) cm = fmaxf(cm, __shfl_xor(cm, msk));
        float mn = fmaxf(m[r], cm);
        al[r] = __expf(m[r] - mn);
        m[r] = mn;
        float psum = 0.0f;
#pragma unroll
        for (int nb = 0; nb < 4; nb++) {
          int idx = db + nb * 16;
          idx = idx < 0 ? 0 : (idx > 182 ? 182 : idx);
          float p = __expf(s[nb][r] - mn) * ebias[idx];
          psum += p;
          Ps[(w * 16 + quad * 4 + r) * 68 + nb * 16 + l15] = (half_t)p;
        }
#pragma unroll
        for (int msk = 1; msk <= 8; msk <<= 1) psum += __shfl_xor(psum, msk);
        l[r] = l[r] * al[r] + psum;
#pragma unroll
        for (int nb = 0; nb < 4; nb++) o[nb][r] *= al[r];
      }
    }

    // ---- O += P V ----
    half8 af[2];
#pragma unroll
    for (int ks = 0; ks < 2; ks++)
      af[ks] = *(half8*)&Ps[(w * 16 + l15) * 68 + ks * 32 + quad * 8];
#pragma unroll
    for (int nb = 0; nb < 4; nb++) {
      int dd = nb * 16 + l15;
      int sw = dd & 7;
#pragma unroll
      for (int ks = 0; ks < 2; ks++) {
        half8 bf = *(half8*)&Vts[dd * 64 + ((ks * 4 + quad) ^ sw) * 8];
        o[nb] = __builtin_amdgcn_mfma_f32_16x16x32_f16(af[ks], bf, o[nb], 0, 0, 0);
      }
    }
  }

  // ---- epilogue: unnormalized partials ----
#pragma unroll
  for (int r = 0; r < 4; r++) {
    int row = bh * S_LEN + q0w + quad * 4 + r;   // bh*2048 + q
    float* op = Opart + (size_t)part * 4194304 + (size_t)row * 64;
#pragma unroll
    for (int nb = 0; nb < 4; nb++) op[nb * 16 + l15] = o[nb][r];
    if (l15 == 0) {
      Mp[part * 65536 + row] = m[r];
      Lp[part * 65536 + row] = l[r];
    }
  }
}

// ---------------------------------------------------------------------------
// Merge the 2 split-K partials: exact flash-decode combine, write X fp16.
// One thread per output element. grid = 4194304/256.
// ---------------------------------------------------------------------------
__global__ __launch_bounds__(256) void attn_combine(const float* __restrict__ Opart,
                                                    const float* __restrict__ Mp,
                                                    const float* __restrict__ Lp,
                                                    half_t* __restrict__ X) {
  int idx = blockIdx.x * 256 + threadIdx.x;
  int row = idx >> 6;        // bh*2048 + q
  int d = idx & 63;
  float m0 = Mp[row], m1 = Mp[65536 + row];
  float l0 = Lp[row], l1 = Lp[65536 + row];
  float M = fmaxf(m0, m1);
  float a0 = __expf(m0 - M), a1 = __expf(m1 - M);
  float L = l0 * a0 + l1 * a1;
  float o = (Opart[(size_t)row * 64 + d] * a0 +
             Opart[4194304 + (size_t)row * 64 + d] * a1) / L;
  int bh = row >> 11, q = row & (S_LEN - 1);
  int b = bh >> 4, h = bh & (NH - 1);
  X[(size_t)(b * S_LEN + q) * DMODEL + h * DKV + d] = (half_t)o;
}

// ---------------------------------------------------------------------------
// kernel_launch
// ws layout (halves): Ah 4M (reused as Vt) | Wqt 3M | Wot 1M | Qh 4M | Kh 4M |
//   Vh 4M | Xh 4M | then f32: Opart 8.39M | Mp 131072 | Lp 131072  (~90 MB)
// ---------------------------------------------------------------------------
extern "C" void kernel_launch(void* const* d_in, const int* in_sizes, int n_in,
                              void* d_out, int out_size, void* d_ws, size_t ws_size,
                              hipStream_t stream) {
  const float* hidden = (const float*)d_in[0];
  const float* w_qkv = (const float*)d_in[1];
  const float* w_o = (const float*)d_in[2];
  const float* table = (const float*)d_in[3];

  float* attn_out = (float*)d_out;
  float* bias_out = (float*)d_out + 4194304;

  half_t* Ah  = (half_t*)d_ws;     // hidden fp16; reused as Vt after hgemm1
  half_t* Wqt = Ah + 4194304;      // [3072][1024]
  half_t* Wot = Wqt + 3145728;     // [1024][1024]
  half_t* Qh  = Wot + 1048576;     // [b,h,s,d]
  half_t* Kh  = Qh + 4194304;      // [b,h,s,d]
  half_t* Vh  = Kh + 4194304;      // [b,h,s,d]
  half_t* Xh  = Vh + 4194304;      // [4096][1024]
  half_t* Vth = Ah;                // [b,h,d,s] (aliases Ah; Ah dead by then)
  float* Opart = (float*)(Xh + 4194304);   // 2 x 4,194,304 f32
  float* Mpp   = Opart + 8388608;          // 2 x 65536
  float* Lpp   = Mpp + 131072;             // 2 x 65536

  // prep: casts + weight transposes + position_bias
  cast_f2h<<<4096, 256, 0, stream>>>(hidden, Ah);
  transpose_cast<<<dim3(3072 / 32, 1024 / 32), 256, 0, stream>>>(w_qkv, Wqt, 1024, 3072);
  transpose_cast<<<dim3(1024 / 32, 1024 / 32), 256, 0, stream>>>(w_o, Wot, 1024, 1024);
  bias_kernel<<<NH * S_LEN, 256, 0, stream>>>(table, bias_out);

  // QKV projection (fp16 MFMA, coalesced scatter epilogue)
  hgemm128<1><<<dim3(3072 / 128, 4096 / 128), 256, 0, stream>>>(
      Ah, Wqt, nullptr, Qh, Kh, Vh, 4096, 3072, 1024);

  // V -> Vt transpose (Ah is dead now; Vt aliases it)
  vtrans<<<dim3(S_LEN / 64, BATCH * NH), 256, 0, stream>>>(Vh, Vth);

  // split-K fp16 MFMA flash attention -> partials, then combine -> Xh
  attn_split<<<dim3((S_LEN / 64) * 2, BATCH * NH), 256, 0, stream>>>(
      Qh, Kh, Vth, table, Opart, Mpp, Lpp);
  attn_combine<<<4194304 / 256, 256, 0, stream>>>(Opart, Mpp, Lpp, Xh);

  // output projection (fp16 MFMA) -> d_out fp32
  hgemm128<0><<<dim3(1024 / 128, 4096 / 128), 256, 0, stream>>>(
      Xh, Wot, attn_out, nullptr, nullptr, nullptr, 4096, 1024, 1024);
}